// Round 6
// baseline (318.354 us; speedup 1.0000x reference)
//
#include <hip/hip_runtime.h>
#include <cstdint>
#include <cstddef>

typedef __bf16 bf16;
typedef __bf16 bf16x4 __attribute__((ext_vector_type(4)));
typedef __bf16 bf16x8 __attribute__((ext_vector_type(8)));
typedef float  f32x4  __attribute__((ext_vector_type(4)));

#define MDIM 2048
#define NDIM 4096
#define KDIM 4096
#define FLOATMAX 3.402823466e38f

// ---------------- fp32 -> bf16 conversion (one launch for both tensors) ----------------
__global__ void cvt2_f32_to_bf16(const float* __restrict__ x, const float* __restrict__ w,
                                 bf16* __restrict__ xb, bf16* __restrict__ wb,
                                 int xn4, int wn4) {
    const int stride = gridDim.x * blockDim.x;
    int i = blockIdx.x * blockDim.x + threadIdx.x;
    for (int k = i; k < xn4; k += stride) {
        f32x4 v = reinterpret_cast<const f32x4*>(x)[k];
        reinterpret_cast<bf16x4*>(xb)[k] = __builtin_convertvector(v, bf16x4);
    }
    for (int k = i; k < wn4; k += stride) {
        f32x4 v = reinterpret_cast<const f32x4*>(w)[k];
        reinterpret_cast<bf16x4*>(wb)[k] = __builtin_convertvector(v, bf16x4);
    }
}

// async global->LDS, 16B per lane (HW: wave-uniform LDS base + lane*16)
__device__ __forceinline__ void g2lds16(const bf16* g, bf16* l) {
    __builtin_amdgcn_global_load_lds(
        (const __attribute__((address_space(1))) uint32_t*)g,
        (__attribute__((address_space(3))) uint32_t*)l, 16, 0, 0);
}

// ---------------- MAM main kernel ----------------
// Block tile 128(m) x 128(n); 256 threads = 4 waves in 2(m) x 2(n); wave tile 64x64
// (32 FLOP per LDS byte; LDS-read floor ~40 us, MFMA 33 us, VALU 14 us).
// REGISTER MODEL (R3/R4/R5 lessons): allocator splits the unified file 128 arch-VGPR
// + 128 AGPR (mx+mn fill the AGPR side). ALL loop state must fit 128 arch VGPRs.
// R5's per-i sched regions still let the scheduler batch 8 MFMA results (32 regs)
// -> arch demand ~120 vs 128 cap -> ~6 regs spilled/stage (WRITE_SIZE 263 MB).
// Fix: sched_barrier(0) after EACH (i,j) pair -> only one (s0,s1) pair (8 regs)
// live per region; arch demand ~86, 40-reg slack. max3/min3 retained.
// MFMA->VALU latency at region boundaries is hidden by the co-resident wave
// (2 blocks/CU -> 2 waves/SIMD).
// K: 64 stages of BK=64 (2 ACCBLOCKs each); SPLITS=2 sequential: after stage 31
// store partial (mx+mn) to out (race-free, idempotent), reset; epilogue adds
// stored + split1 + bias (same-thread RMW).
// LDS double-buffered (64 KB): one barrier per stage, prefetch overlaps compute.
// Staging uses XOR chunk swizzle so fragment ds_read_b128 is 2-way conflict-free.
__global__ __launch_bounds__(256, 2) void mam_kernel(
    const bf16* __restrict__ A,   // [M,K] bf16 (x)
    const bf16* __restrict__ B,   // [N,K] bf16 (weight row n = col n of w)
    const float* __restrict__ bias,
    float* __restrict__ out)
{
    __shared__ __align__(16) bf16 sA[2][2][128 * 32];  // [parity][accblock-half]
    __shared__ __align__(16) bf16 sB[2][2][128 * 32];

    const int t    = threadIdx.x;
    const int lane = t & 63;
    const int w    = t >> 6;        // 0..3
    const int wm   = (w >> 1) * 64; // 0 or 64
    const int wn   = (w & 1) * 64;  // 0 or 64

    const int m0 = blockIdx.y * 128;
    const int n0 = blockIdx.x * 128;

    // staging: thread t -> row r = t>>2 (0..63; second row-block handled at +64),
    // slot p = t&3; fetches global chunk c = p ^ ((r>>1)&3).
    // ((r+64)>>1)&3 == (r>>1)&3, so the same chunk choice serves both row-blocks.
    const int srow   = t >> 2;
    const int spos   = t & 3;
    const int schunk = spos ^ ((srow >> 1) & 3);
    const bf16* gA = A + (size_t)(m0 + srow) * KDIM + schunk * 8;
    const bf16* gB = B + (size_t)(n0 + srow) * KDIM + schunk * 8;
    const int ldst = t * 8;  // LDS dest: lane-contiguous 16B per 2048-elem region

    // fragment addressing: row R, chunk q=lane>>4 lives at slot q ^ ((R>>1)&3)
    const int frow = lane & 15;
    const int q    = lane >> 4;
    int offA[4], offB[4];
#pragma unroll
    for (int i = 0; i < 4; ++i) {
        const int Ra = wm + i * 16 + frow;
        offA[i] = Ra * 32 + (q ^ ((Ra >> 1) & 3)) * 8;
        const int Rb = wn + i * 16 + frow;
        offB[i] = Rb * 32 + (q ^ ((Rb >> 1) & 3)) * 8;
    }

    const f32x4 kZero = {0.f, 0.f, 0.f, 0.f};

    f32x4 mx[4][4], mn[4][4];
#pragma unroll
    for (int i = 0; i < 4; ++i)
#pragma unroll
        for (int j = 0; j < 4; ++j) {
            mx[i][j] = (f32x4)(-FLOATMAX);
            mn[i][j] = (f32x4)(FLOATMAX);
        }

    auto prefetch = [&](int s, int pb) {
        const bf16* ga = gA + (size_t)s * 64;
        const bf16* gb = gB + (size_t)s * 64;
        // [half][row-block]: row-block 1 = rows 64..127 -> +64*KDIM src, +2048 dst
        g2lds16(ga,                  &sA[pb][0][ldst]);
        g2lds16(ga + 64 * KDIM,      &sA[pb][0][2048 + ldst]);
        g2lds16(ga + 32,             &sA[pb][1][ldst]);
        g2lds16(ga + 64 * KDIM + 32, &sA[pb][1][2048 + ldst]);
        g2lds16(gb,                  &sB[pb][0][ldst]);
        g2lds16(gb + 64 * KDIM,      &sB[pb][0][2048 + ldst]);
        g2lds16(gb + 32,             &sB[pb][1][ldst]);
        g2lds16(gb + 64 * KDIM + 32, &sB[pb][1][2048 + ldst]);
    };

    auto compute = [&](int pb) {
        // B-fragments resident for the whole stage (8 x bf16x8 = 32 VGPRs)
        bf16x8 bF0[4], bF1[4];
#pragma unroll
        for (int j = 0; j < 4; ++j) {
            bF0[j] = *(const bf16x8*)&sB[pb][0][offB[j]];
            bF1[j] = *(const bf16x8*)&sB[pb][1][offB[j]];
        }
        // stream A-fragments; sched_barrier(0) after EACH (i,j) so at most one
        // (s0,s1) MFMA-result pair is live -> arch-VGPR demand ~86 of 128.
#pragma unroll
        for (int i = 0; i < 4; ++i) {
            const bf16x8 a0 = *(const bf16x8*)&sA[pb][0][offA[i]];
            const bf16x8 a1 = *(const bf16x8*)&sA[pb][1][offA[i]];
#pragma unroll
            for (int j = 0; j < 4; ++j) {
                f32x4 s0 = __builtin_amdgcn_mfma_f32_16x16x32_bf16(
                    a0, bF0[j], kZero, 0, 0, 0);
                f32x4 s1 = __builtin_amdgcn_mfma_f32_16x16x32_bf16(
                    a1, bF1[j], kZero, 0, 0, 0);
#pragma unroll
                for (int r = 0; r < 4; ++r) {
                    mx[i][j][r] = fmaxf(fmaxf(mx[i][j][r], s0[r]), s1[r]);  // v_max3_f32
                    mn[i][j][r] = fminf(fminf(mn[i][j][r], s0[r]), s1[r]);  // v_min3_f32
                }
                __builtin_amdgcn_sched_barrier(0);
            }
        }
    };

    // C/D layout: col=lane&15, row=(lane>>4)*4+reg
    const int orow = (lane >> 4) * 4;
    const int ocol = lane & 15;

    prefetch(0, 0);

    int bb = 0;
    // ---- split 0: stages 0..31 ----
#pragma unroll 1
    for (int it = 0; it < 16; ++it) {
        __syncthreads();
        prefetch(bb + 1, 1);   // bb even <= 30 -> bb+1 <= 31
        compute(0);
        ++bb;
        __syncthreads();
        prefetch(bb + 1, 0);   // bb odd <= 31 -> bb+1 <= 32 (stage 32, parity 0)
        compute(1);
        ++bb;
    }

    // store split-0 partial to out (race-free, idempotent), reset mx/mn
#pragma unroll
    for (int j = 0; j < 4; ++j) {
        const int col = n0 + wn + j * 16 + ocol;
#pragma unroll
        for (int i = 0; i < 4; ++i) {
            const int row = m0 + wm + i * 16 + orow;
#pragma unroll
            for (int r = 0; r < 4; ++r)
                out[(size_t)(row + r) * NDIM + col] = mx[i][j][r] + mn[i][j][r];
            mx[i][j] = (f32x4)(-FLOATMAX);
            mn[i][j] = (f32x4)(FLOATMAX);
        }
    }

    // ---- split 1: stages 32..63 ----
#pragma unroll 1
    for (int it = 0; it < 16; ++it) {
        __syncthreads();
        prefetch(bb + 1, 1);   // bb=32 -> prefetch 33 into parity 1
        compute(0);
        ++bb;
        __syncthreads();
        if (bb < 63) prefetch(bb + 1, 0);
        compute(1);
        ++bb;
    }

    // epilogue: out = split0(stored) + split1(mx+mn) + bias; same-thread RMW, race-free
#pragma unroll
    for (int j = 0; j < 4; ++j) {
        const int col = n0 + wn + j * 16 + ocol;
        const float bv = bias[col];
#pragma unroll
        for (int i = 0; i < 4; ++i) {
            const int row = m0 + wm + i * 16 + orow;
#pragma unroll
            for (int r = 0; r < 4; ++r) {
                const size_t idx = (size_t)(row + r) * NDIM + col;
                out[idx] = out[idx] + (mx[i][j][r] + mn[i][j][r]) + bv;
            }
        }
    }
}

extern "C" void kernel_launch(void* const* d_in, const int* in_sizes, int n_in,
                              void* d_out, int out_size, void* d_ws, size_t ws_size,
                              hipStream_t stream) {
    const float* x    = (const float*)d_in[0];  // [M,K]
    const float* wgt  = (const float*)d_in[1];  // [N,K]
    const float* bias = (const float*)d_in[2];  // [N]
    float* out = (float*)d_out;

    bf16* xbf = (bf16*)d_ws;                        // M*K bf16 = 16 MiB
    bf16* wbf = xbf + (size_t)MDIM * KDIM;          // N*K bf16 = 32 MiB

    const int xn4 = (MDIM * KDIM) / 4;
    const int wn4 = (NDIM * KDIM) / 4;
    cvt2_f32_to_bf16<<<dim3(4096), dim3(256), 0, stream>>>(x, wgt, xbf, wbf, xn4, wn4);

    dim3 grid(NDIM / 128, MDIM / 128);  // (32, 16)
    mam_kernel<<<grid, dim3(256), 0, stream>>>(xbf, wbf, bias, out);
}

// Round 7
// 314.661 us; speedup vs baseline: 1.0117x; 1.0117x over previous
//
#include <hip/hip_runtime.h>
#include <cstdint>
#include <cstddef>

typedef __bf16 bf16;
typedef __bf16 bf16x4 __attribute__((ext_vector_type(4)));
typedef __bf16 bf16x8 __attribute__((ext_vector_type(8)));
typedef float  f32x4  __attribute__((ext_vector_type(4)));

#define MDIM 2048
#define NDIM 4096
#define KDIM 4096
#define FLOATMAX 3.402823466e38f

// ---------------- fp32 -> bf16 conversion (one launch for both tensors) ----------------
__global__ void cvt2_f32_to_bf16(const float* __restrict__ x, const float* __restrict__ w,
                                 bf16* __restrict__ xb, bf16* __restrict__ wb,
                                 int xn4, int wn4) {
    const int stride = gridDim.x * blockDim.x;
    int i = blockIdx.x * blockDim.x + threadIdx.x;
    for (int k = i; k < xn4; k += stride) {
        f32x4 v = reinterpret_cast<const f32x4*>(x)[k];
        reinterpret_cast<bf16x4*>(xb)[k] = __builtin_convertvector(v, bf16x4);
    }
    for (int k = i; k < wn4; k += stride) {
        f32x4 v = reinterpret_cast<const f32x4*>(w)[k];
        reinterpret_cast<bf16x4*>(wb)[k] = __builtin_convertvector(v, bf16x4);
    }
}

// async global->LDS, 16B per lane (HW: wave-uniform LDS base + lane*16)
__device__ __forceinline__ void g2lds16(const bf16* g, bf16* l) {
    __builtin_amdgcn_global_load_lds(
        (const __attribute__((address_space(1))) uint32_t*)g,
        (__attribute__((address_space(3))) uint32_t*)l, 16, 0, 0);
}

// ---------------- MAM main kernel ----------------
// Block tile 128(m) x 128(n); 256 threads = 4 waves in 2(m) x 2(n); wave tile 64x64
// (32 FLOP per LDS byte; LDS-read floor ~40 us, MFMA 33 us, VALU 14 us).
// REGISTER LESSON (R3-R6): with __launch_bounds__(256,2) the 256-reg hard cap sits
// right at the design's true demand (~200-250: 128 acc + 32 B-frags + A/s-temps +
// addressing) -> the allocator spills ~200 MB of scratch regardless of sched_barrier
// region structure (WRITE_SIZE 220/263/279 MB across three scheduling variants).
// Fix: NO waves cap (launch_bounds(256) -> 512-reg ceiling). Compiler allocates what
// it needs (~230), zero spill; occupancy lands at 2 waves/SIMD by registers and
// 2 blocks/CU by LDS (64 KB dbuf) - same residency as before, without the spill.
// All sched_barriers removed (they serialized ds_read latency; MfmaUtil stuck 14%).
// Fragment addressing: (R>>1)&3 == (frow>>1)&3 (independent of i and wm), so
// offsets collapse to offA0/offB0 + i*512 elems; i*512 folds into ds_read imm.
// K: 64 stages of BK=64 (2 ACCBLOCKs each); SPLITS=2 sequential: after stage 31
// store partial (mx+mn) to out (race-free, idempotent), reset; epilogue adds
// stored + split1 + bias (same-thread RMW).
// LDS double-buffered (64 KB): one barrier per stage, prefetch overlaps compute.
// Staging uses XOR chunk swizzle so fragment ds_read_b128 is 2-way conflict-free.
__global__ __launch_bounds__(256) void mam_kernel(
    const bf16* __restrict__ A,   // [M,K] bf16 (x)
    const bf16* __restrict__ B,   // [N,K] bf16 (weight row n = col n of w)
    const float* __restrict__ bias,
    float* __restrict__ out)
{
    __shared__ __align__(16) bf16 sA[2][2][128 * 32];  // [parity][accblock-half]
    __shared__ __align__(16) bf16 sB[2][2][128 * 32];

    const int t    = threadIdx.x;
    const int lane = t & 63;
    const int w    = t >> 6;        // 0..3
    const int wm   = (w >> 1) * 64; // 0 or 64
    const int wn   = (w & 1) * 64;  // 0 or 64

    const int m0 = blockIdx.y * 128;
    const int n0 = blockIdx.x * 128;

    // staging: thread t -> row r = t>>2 (0..63; second row-block handled at +64),
    // slot p = t&3; fetches global chunk c = p ^ ((r>>1)&3).
    // ((r+64)>>1)&3 == (r>>1)&3, so the same chunk choice serves both row-blocks.
    const int srow   = t >> 2;
    const int spos   = t & 3;
    const int schunk = spos ^ ((srow >> 1) & 3);
    const bf16* gA = A + (size_t)(m0 + srow) * KDIM + schunk * 8;
    const bf16* gB = B + (size_t)(n0 + srow) * KDIM + schunk * 8;
    const int ldst = t * 8;  // LDS dest: lane-contiguous 16B per 2048-elem region

    // fragment addressing: row R, chunk q=lane>>4 lives at slot q ^ ((R>>1)&3);
    // (R>>1)&3 = (frow>>1)&3 for all i,wm (i*16 and wm are multiples of 16).
    const int frow = lane & 15;
    const int q    = lane >> 4;
    const int swz  = (q ^ ((frow >> 1) & 3)) * 8;
    const int offA0 = (wm + frow) * 32 + swz;   // + i*512 elems per i
    const int offB0 = (wn + frow) * 32 + swz;   // + j*512 elems per j

    const f32x4 kZero = {0.f, 0.f, 0.f, 0.f};

    f32x4 mx[4][4], mn[4][4];
#pragma unroll
    for (int i = 0; i < 4; ++i)
#pragma unroll
        for (int j = 0; j < 4; ++j) {
            mx[i][j] = (f32x4)(-FLOATMAX);
            mn[i][j] = (f32x4)(FLOATMAX);
        }

    auto prefetch = [&](int s, int pb) {
        const bf16* ga = gA + (size_t)s * 64;
        const bf16* gb = gB + (size_t)s * 64;
        // [half][row-block]: row-block 1 = rows 64..127 -> +64*KDIM src, +2048 dst
        g2lds16(ga,                  &sA[pb][0][ldst]);
        g2lds16(ga + 64 * KDIM,      &sA[pb][0][2048 + ldst]);
        g2lds16(ga + 32,             &sA[pb][1][ldst]);
        g2lds16(ga + 64 * KDIM + 32, &sA[pb][1][2048 + ldst]);
        g2lds16(gb,                  &sB[pb][0][ldst]);
        g2lds16(gb + 64 * KDIM,      &sB[pb][0][2048 + ldst]);
        g2lds16(gb + 32,             &sB[pb][1][ldst]);
        g2lds16(gb + 64 * KDIM + 32, &sB[pb][1][2048 + ldst]);
    };

    auto compute = [&](int pb) {
        // B-fragments resident for the whole stage (8 x bf16x8 = 32 VGPRs)
        bf16x8 bF0[4], bF1[4];
#pragma unroll
        for (int j = 0; j < 4; ++j) {
            bF0[j] = *(const bf16x8*)&sB[pb][0][offB0 + j * 512];
            bF1[j] = *(const bf16x8*)&sB[pb][1][offB0 + j * 512];
        }
        // stream A-fragments (source order; scheduler free to arrange under the
        // relaxed 512-reg ceiling)
#pragma unroll
        for (int i = 0; i < 4; ++i) {
            const bf16x8 a0 = *(const bf16x8*)&sA[pb][0][offA0 + i * 512];
            const bf16x8 a1 = *(const bf16x8*)&sA[pb][1][offA0 + i * 512];
#pragma unroll
            for (int j = 0; j < 4; ++j) {
                f32x4 s0 = __builtin_amdgcn_mfma_f32_16x16x32_bf16(
                    a0, bF0[j], kZero, 0, 0, 0);
                f32x4 s1 = __builtin_amdgcn_mfma_f32_16x16x32_bf16(
                    a1, bF1[j], kZero, 0, 0, 0);
#pragma unroll
                for (int r = 0; r < 4; ++r) {
                    mx[i][j][r] = fmaxf(fmaxf(mx[i][j][r], s0[r]), s1[r]);  // v_max3_f32
                    mn[i][j][r] = fminf(fminf(mn[i][j][r], s0[r]), s1[r]);  // v_min3_f32
                }
            }
        }
    };

    // C/D layout: col=lane&15, row=(lane>>4)*4+reg
    const int orow = (lane >> 4) * 4;
    const int ocol = lane & 15;

    prefetch(0, 0);

    int bb = 0;
    // ---- split 0: stages 0..31 ----
#pragma unroll 1
    for (int it = 0; it < 16; ++it) {
        __syncthreads();
        prefetch(bb + 1, 1);   // bb even <= 30 -> bb+1 <= 31
        compute(0);
        ++bb;
        __syncthreads();
        prefetch(bb + 1, 0);   // bb odd <= 31 -> bb+1 <= 32 (stage 32, parity 0)
        compute(1);
        ++bb;
    }

    // store split-0 partial to out (race-free, idempotent), reset mx/mn
#pragma unroll
    for (int j = 0; j < 4; ++j) {
        const int col = n0 + wn + j * 16 + ocol;
#pragma unroll
        for (int i = 0; i < 4; ++i) {
            const int row = m0 + wm + i * 16 + orow;
#pragma unroll
            for (int r = 0; r < 4; ++r)
                out[(size_t)(row + r) * NDIM + col] = mx[i][j][r] + mn[i][j][r];
            mx[i][j] = (f32x4)(-FLOATMAX);
            mn[i][j] = (f32x4)(FLOATMAX);
        }
    }

    // ---- split 1: stages 32..63 ----
#pragma unroll 1
    for (int it = 0; it < 16; ++it) {
        __syncthreads();
        prefetch(bb + 1, 1);   // bb=32 -> prefetch 33 into parity 1
        compute(0);
        ++bb;
        __syncthreads();
        if (bb < 63) prefetch(bb + 1, 0);
        compute(1);
        ++bb;
    }

    // epilogue: out = split0(stored) + split1(mx+mn) + bias; same-thread RMW, race-free
#pragma unroll
    for (int j = 0; j < 4; ++j) {
        const int col = n0 + wn + j * 16 + ocol;
        const float bv = bias[col];
#pragma unroll
        for (int i = 0; i < 4; ++i) {
            const int row = m0 + wm + i * 16 + orow;
#pragma unroll
            for (int r = 0; r < 4; ++r) {
                const size_t idx = (size_t)(row + r) * NDIM + col;
                out[idx] = out[idx] + (mx[i][j][r] + mn[i][j][r]) + bv;
            }
        }
    }
}

extern "C" void kernel_launch(void* const* d_in, const int* in_sizes, int n_in,
                              void* d_out, int out_size, void* d_ws, size_t ws_size,
                              hipStream_t stream) {
    const float* x    = (const float*)d_in[0];  // [M,K]
    const float* wgt  = (const float*)d_in[1];  // [N,K]
    const float* bias = (const float*)d_in[2];  // [N]
    float* out = (float*)d_out;

    bf16* xbf = (bf16*)d_ws;                        // M*K bf16 = 16 MiB
    bf16* wbf = xbf + (size_t)MDIM * KDIM;          // N*K bf16 = 32 MiB

    const int xn4 = (MDIM * KDIM) / 4;
    const int wn4 = (NDIM * KDIM) / 4;
    cvt2_f32_to_bf16<<<dim3(4096), dim3(256), 0, stream>>>(x, wgt, xbf, wbf, xn4, wn4);

    dim3 grid(NDIM / 128, MDIM / 128);  // (32, 16)
    mam_kernel<<<grid, dim3(256), 0, stream>>>(xbf, wbf, bias, out);
}